// Round 7
// baseline (468.212 us; speedup 1.0000x reference)
//
#include <hip/hip_runtime.h>
#include <stdint.h>

#define N_NODES 100000
#define N_EDGES 1000000
#define DIM 256
#define CAP 32            // fixed neighbor-slot capacity per node (Poisson(10) graph)

typedef __attribute__((ext_vector_type(8))) short short8;          // bf16 MFMA frag (4 VGPR)
typedef __attribute__((ext_vector_type(4))) float f32x4;           // fp32 C/D frag / NT ops
typedef __attribute__((ext_vector_type(4))) unsigned short u16x4;  // 8B bf16 chunk

__device__ inline float b2f(unsigned short u) {
    union { unsigned int i; float f; } v; v.i = ((unsigned int)u) << 16; return v.f;
}
__device__ inline unsigned short f2b(float f) {   // round-to-nearest-even
    union { float f; unsigned int i; } v; v.f = f;
    unsigned int u = v.i;
    return (unsigned short)((u + 0x7FFFu + ((u >> 16) & 1u)) >> 16);
}

// ---------------- workspace layout (bytes) ----------------
// cnt    u32 N          @ 0          (raw in-degree; may exceed CAP)
// ovfCnt u32            @ 400000
// colM   i32 N*CAP      @ 400256     (12.8 MB; NOT zeroed — gather clamps indices)
// wgt    f32 N          @ 13200256   (rsqrt(cnt+1), precomputed once)
// ovf    u32 pairs E    @ 13600256   (8 MB: worst-case-correct overflow list)
// Wt1    bf16 256x256   @ 21600256   (n-major, k contiguous)
// Wt2    bf16 256x256   @ 21731328
// xs     bf16 N*256     @ 21862400   (raw bf16 features)
// z1s    bf16 N*256     @ 73062400   (raw bf16 layer-1 relu output)
// agg    bf16 N*256     @ 124262400  (gather output, reused by both layers)
// total 175.5 MB. memset range [0, 400256) covers cnt | ovfCnt only.

#define NB_FILL 245    // ceil(1M / 4096); 16 edges/thread (ILP-16 atomic chains)
#define NB_PACK 512
#define NB_CVT  25000  // N*256/4 float4 elems / 256 threads

// ONE preprocessing kernel: bucket-fill (blocks [0,245), latency/atomic-bound,
// 16 independent edges per thread to hide the atomicAdd round trip) + W1/W2
// pack + x->bf16 convert (BW-bound, overlaps fill).
__global__ void k_pre(const int* __restrict__ src, const int* __restrict__ dst,
                      uint32_t* __restrict__ cnt, uint32_t* __restrict__ ovfCnt,
                      int* __restrict__ colM, uint32_t* __restrict__ ovf,
                      const float* __restrict__ W1, const float* __restrict__ W2,
                      unsigned short* __restrict__ Wt1, unsigned short* __restrict__ Wt2,
                      const float* __restrict__ x, unsigned short* __restrict__ xs) {
    int b = blockIdx.x, t = threadIdx.x;
    if (b < NB_FILL) {
        int e = b * 4096 + t;
        #pragma unroll
        for (int k = 0; k < 16; ++k, e += 256) {   // 16 independent atomic chains
            if (e < N_EDGES) {
                unsigned d = (unsigned)dst[e];
                unsigned s = (unsigned)src[e];
                if (d < N_NODES && s < N_NODES) {
                    uint32_t p = atomicAdd(&cnt[d], 1u);
                    if (p < CAP) colM[(size_t)d * CAP + p] = (int)s;
                    else {       // correctness fallback; statistically never taken
                        uint32_t o = atomicAdd(ovfCnt, 1u);
                        if (o < (uint32_t)N_EDGES) { ovf[2 * o] = d; ovf[2 * o + 1] = s; }
                    }
                }
            }
        }
    } else if (b < NB_FILL + NB_PACK) {
        int n = b - NB_FILL;
        if (n < 256) Wt1[n * 256 + t] = f2b(W1[t * 256 + n]);
        else { n -= 256; Wt2[n * 256 + t] = f2b(W2[t * 256 + n]); }
    } else {
        int i = (b - (NB_FILL + NB_PACK)) * 256 + t;   // float4 index, exactly N*64
        f32x4 v = __builtin_nontemporal_load((const f32x4*)x + i);  // read-once stream
        u16x4 o;
        o.x = f2b(v.x); o.y = f2b(v.y); o.z = f2b(v.z); o.w = f2b(v.w);
        *((u16x4*)xs + i) = o;                          // re-read by gather -> cacheable
    }
}

// wgt[n] = rsqrt(cnt[n]+1): hoists the per-edge int->float + rsqrt out of the
// gather hot loop.
__global__ void k_wgt(const uint32_t* __restrict__ cnt, float* __restrict__ wgt) {
    int n = blockIdx.x * blockDim.x + threadIdx.x;
    if (n < N_NODES) wgt[n] = rsqrtf((float)(cnt[n] + 1u));
}

// DE-FUSED gather — designed for the 64-reg occupancy bucket (32 waves/CU).
// Rounds 3/5/6 post-mortems: occupancy steps at 64/128 total regs/wave; the
// fused kernel sits at exactly 64 VGPR + 64 AGPR = 128 -> capped at 16
// waves/CU, and gather BW scaled ~linearly with waves in every round. This
// kernel has NO LDS and NO MFMA state: one wave = one NODE, 8 B/lane (u16x4)
// row loads (64 lanes x 8 B = 512 B/instr, same bytes/instr as before but
// HALF the row registers: 8 rows in flight = 16 VGPRs). Neighbor index and
// weight loads are wave-UNIFORM (one broadcast line each). ~54 live VGPRs ->
// __launch_bounds__(256,8) forces the <=64 bucket WITHOUT spilling (round-3's
// disaster was capping a ~70-reg kernel at 48; this caps ~54 at 64).
// colM is NOT zeroed: indices clamped with min(ix,N-1); (j+i<dg ? w : 0)
// masks the contribution (0 * finite = 0, no NaN).
// Arithmetic order per element is IDENTICAL to the fused version (absmax is
// exactly at threshold; no reassociation allowed).
__global__ __launch_bounds__(256, 8) void k_gather(
        const unsigned short* __restrict__ rows, const uint32_t* __restrict__ cnt,
        const float* __restrict__ wgt,
        const uint32_t* __restrict__ ovfCnt, const int* __restrict__ colM,
        const uint32_t* __restrict__ ovf, unsigned short* __restrict__ out) {
    int wave = threadIdx.x >> 6, lane = threadIdx.x & 63;
    int node = blockIdx.x * 4 + wave;          // grid = 25000 exactly
    const u16x4* r4 = (const u16x4*)rows;

    uint32_t dgRaw = cnt[node];                // true degree (may exceed CAP)
    float    di    = wgt[node];                // rsqrt(deg+1), precomputed
    uint32_t dg    = dgRaw < CAP ? dgRaw : CAP;
    uint32_t ovfN  = *ovfCnt;

    u16x4 sv = r4[(size_t)node * 64 + lane];   // self row (raw bf16)
    float a[4];
    a[0] = di * b2f(sv.x); a[1] = di * b2f(sv.y);
    a[2] = di * b2f(sv.z); a[3] = di * b2f(sv.w);

    const int* cp = colM + (size_t)node * CAP;
    for (uint32_t j = 0; j < dg; j += 8) {     // uniform trip count per wave
        int4 i0 = *(const int4*)(cp + j);      // 8 raw indices (wave-uniform bcast)
        int4 i1 = *(const int4*)(cp + j + 4);
        unsigned x0 = min((unsigned)i0.x, N_NODES - 1u);
        unsigned x1 = min((unsigned)i0.y, N_NODES - 1u);
        unsigned x2 = min((unsigned)i0.z, N_NODES - 1u);
        unsigned x3 = min((unsigned)i0.w, N_NODES - 1u);
        unsigned x4 = min((unsigned)i1.x, N_NODES - 1u);
        unsigned x5 = min((unsigned)i1.y, N_NODES - 1u);
        unsigned x6 = min((unsigned)i1.z, N_NODES - 1u);
        unsigned x7 = min((unsigned)i1.w, N_NODES - 1u);
        u16x4 r0 = r4[(size_t)x0 * 64 + lane]; // 8 independent 8B row loads
        u16x4 r1 = r4[(size_t)x1 * 64 + lane]; // (512 B/wave each, all in flight)
        u16x4 r2 = r4[(size_t)x2 * 64 + lane];
        u16x4 r3 = r4[(size_t)x3 * 64 + lane];
        u16x4 r4v = r4[(size_t)x4 * 64 + lane];
        u16x4 r5 = r4[(size_t)x5 * 64 + lane];
        u16x4 r6 = r4[(size_t)x6 * 64 + lane];
        u16x4 r7 = r4[(size_t)x7 * 64 + lane];
        float w0 = (j + 0 < dg) ? wgt[x0] : 0.f;   // wave-uniform bcast loads
        float w1 = (j + 1 < dg) ? wgt[x1] : 0.f;
        float w2 = (j + 2 < dg) ? wgt[x2] : 0.f;
        float w3 = (j + 3 < dg) ? wgt[x3] : 0.f;
        float w4 = (j + 4 < dg) ? wgt[x4] : 0.f;
        float w5 = (j + 5 < dg) ? wgt[x5] : 0.f;
        float w6 = (j + 6 < dg) ? wgt[x6] : 0.f;
        float w7 = (j + 7 < dg) ? wgt[x7] : 0.f;
        #pragma unroll
        for (int i = 0; i < 4; ++i) {          // identical per-element chain order
            float s = fmaf(w0, b2f(r0[i]), a[i]);
            s = fmaf(w1, b2f(r1[i]), s);
            s = fmaf(w2, b2f(r2[i]), s);
            s = fmaf(w3, b2f(r3[i]), s);
            s = fmaf(w4, b2f(r4v[i]), s);
            s = fmaf(w5, b2f(r5[i]), s);
            s = fmaf(w6, b2f(r6[i]), s);
            s = fmaf(w7, b2f(r7[i]), s);
            a[i] = s;
        }
    }

    if (ovfN) {   // correctness-only path; never taken for this graph
        for (uint32_t k = 0; k < ovfN; ++k) {
            uint32_t od = ovf[2 * k], os = ovf[2 * k + 1];
            if (od == (uint32_t)node) {
                float wv = wgt[os];
                u16x4 rv = r4[(size_t)os * 64 + lane];
                #pragma unroll
                for (int i = 0; i < 4; ++i) a[i] = fmaf(wv, b2f(rv[i]), a[i]);
            }
        }
    }

    u16x4 o;
    o.x = f2b(di * a[0]); o.y = f2b(di * a[1]);
    o.z = f2b(di * a[2]); o.w = f2b(di * a[3]);
    ((u16x4*)out)[(size_t)node * 64 + lane] = o;   // 512 B/wave coalesced
}

// Lean GEMM: C[64 x 256] = relu(agg_tile @ W + b). agg is L3-hot (just
// written by k_gather). Stage tile to XOR-swizzled LDS with coalesced 16B
// loads, then swapped-operand MFMA: acc = mfma(Wt_frag, A_frag, acc) gives
// C^T in-register (D row = output COLUMN) -> float4/ushort4 vector stores.
__global__ __launch_bounds__(256, 4) void k_gemm(
        const unsigned short* __restrict__ A, const unsigned short* __restrict__ Wt,
        const float* __restrict__ bias,
        unsigned short* __restrict__ Cb, float* __restrict__ Cf) {
    __shared__ __align__(16) unsigned short As[64 * 256];   // 32768 B, swizzled

    int tid = threadIdx.x;
    int w = tid >> 6, lane = tid & 63;
    int rowBase = blockIdx.x * 64;

    // stage: 64 rows x 512 B = 2048 x 16B chunks; thread t -> chunks t+256i
    #pragma unroll
    for (int i = 0; i < 8; ++i) {
        int c  = tid + i * 256;
        int r  = c >> 5;            // 32 x 16B chunks per row
        int kb = c & 31;
        int gr = rowBase + r;
        int4 v = {0, 0, 0, 0};
        if (gr < N_NODES) v = *(const int4*)(A + (size_t)gr * 256 + kb * 8);
        *(int4*)((char*)As + r * 512 + ((kb ^ (r & 7)) << 4)) = v;   // swizzled
    }
    __syncthreads();

    int m = lane & 15, quad = lane >> 4;

    f32x4 acc[4][4];
    #pragma unroll
    for (int mt = 0; mt < 4; ++mt)
        #pragma unroll
        for (int nt = 0; nt < 4; ++nt)
            acc[mt][nt] = (f32x4){0.f, 0.f, 0.f, 0.f};

    #pragma unroll
    for (int ks = 0; ks < 8; ++ks) {          // K = 8 steps x 32
        short8 wf[4], xf[4];
        #pragma unroll
        for (int nt = 0; nt < 4; ++nt)
            wf[nt] = *(const short8*)(Wt + (size_t)(w * 64 + nt * 16 + m) * 256 + ks * 32 + quad * 8);
        #pragma unroll
        for (int mt = 0; mt < 4; ++mt) {
            int rl = mt * 16 + m;
            int ch = (ks * 4 + quad) ^ (rl & 7);
            xf[mt] = *(const short8*)((const char*)As + rl * 512 + (ch << 4));
        }
        #pragma unroll
        for (int mt = 0; mt < 4; ++mt)
            #pragma unroll
            for (int nt = 0; nt < 4; ++nt)
                acc[mt][nt] = __builtin_amdgcn_mfma_f32_16x16x32_bf16(
                    wf[nt], xf[mt], acc[mt][nt], 0, 0, 0);
    }

    // epilogue: D row (quad*4+r) = output col, D col (lane&15) = node
    float4 bv[4];
    #pragma unroll
    for (int nt = 0; nt < 4; ++nt)
        bv[nt] = *(const float4*)(bias + w * 64 + nt * 16 + quad * 4);

    #pragma unroll
    for (int mt = 0; mt < 4; ++mt) {
        int node = rowBase + mt * 16 + m;
        if (node >= N_NODES) continue;
        if (Cf) {
            #pragma unroll
            for (int nt = 0; nt < 4; ++nt) {
                int c = w * 64 + nt * 16 + quad * 4;
                f32x4 v = acc[mt][nt];
                f32x4 o;
                o.x = fmaxf(v[0] + bv[nt].x, 0.f);
                o.y = fmaxf(v[1] + bv[nt].y, 0.f);
                o.z = fmaxf(v[2] + bv[nt].z, 0.f);
                o.w = fmaxf(v[3] + bv[nt].w, 0.f);
                // final output never re-read -> NT store, keep caches for gather rows
                __builtin_nontemporal_store(o, (f32x4*)(Cf + (size_t)node * 256 + c));
            }
        } else {
            #pragma unroll
            for (int nt = 0; nt < 4; ++nt) {
                int c = w * 64 + nt * 16 + quad * 4;
                f32x4 v = acc[mt][nt];
                u16x4 o;   // raw relu, bf16 (layer-2 gather applies weights itself)
                o.x = f2b(fmaxf(v[0] + bv[nt].x, 0.f));
                o.y = f2b(fmaxf(v[1] + bv[nt].y, 0.f));
                o.z = f2b(fmaxf(v[2] + bv[nt].z, 0.f));
                o.w = f2b(fmaxf(v[3] + bv[nt].w, 0.f));
                *(u16x4*)(Cb + (size_t)node * 256 + c) = o;
            }
        }
    }
}

extern "C" void kernel_launch(void* const* d_in, const int* in_sizes, int n_in,
                              void* d_out, int out_size, void* d_ws, size_t ws_size,
                              hipStream_t stream) {
    const int*   edge = (const int*)d_in[0];   // [2][E]: row0 = src, row1 = dst
    const float* x    = (const float*)d_in[1];
    const float* W1   = (const float*)d_in[2];
    const float* b1   = (const float*)d_in[3];
    const float* W2   = (const float*)d_in[4];
    const float* b2   = (const float*)d_in[5];
    float* out = (float*)d_out;

    char* ws = (char*)d_ws;
    uint32_t*       cnt    = (uint32_t*)(ws + 0);
    uint32_t*       ovfCnt = (uint32_t*)(ws + 400000);
    int*            colM   = (int*)     (ws + 400256);
    float*          wgt    = (float*)   (ws + 13200256);
    uint32_t*       ovf    = (uint32_t*)(ws + 13600256);
    unsigned short* Wt1    = (unsigned short*)(ws + 21600256);
    unsigned short* Wt2    = (unsigned short*)(ws + 21731328);
    unsigned short* xs     = (unsigned short*)(ws + 21862400);
    unsigned short* z1s    = (unsigned short*)(ws + 73062400ull);
    unsigned short* agg    = (unsigned short*)(ws + 124262400ull);

    const int* src = edge;
    const int* dst = edge + N_EDGES;

    // zero cnt + ovfCnt only (colM not zeroed: gather clamps indices)
    hipMemsetAsync(ws, 0, 400256, stream);

    // all heavy preprocessing in one launch: fill || pack || cvt
    k_pre<<<NB_FILL + NB_PACK + NB_CVT, 256, 0, stream>>>(
        src, dst, cnt, ovfCnt, colM, ovf, W1, W2, Wt1, Wt2, x, xs);
    // tiny: per-node weight table
    k_wgt<<<(N_NODES + 255) / 256, 256, 0, stream>>>(cnt, wgt);

    // layer 1: gather (32 waves/CU) then lean GEMM
    k_gather<<<N_NODES / 4, 256, 0, stream>>>(xs, cnt, wgt, ovfCnt, colM, ovf, agg);
    k_gemm<<<(N_NODES + 63) / 64, 256, 0, stream>>>(agg, Wt1, b1, z1s, nullptr);
    // layer 2
    k_gather<<<N_NODES / 4, 256, 0, stream>>>(z1s, cnt, wgt, ovfCnt, colM, ovf, agg);
    k_gemm<<<(N_NODES + 63) / 64, 256, 0, stream>>>(agg, Wt2, b2, nullptr, out);
}

// Round 8
// 454.607 us; speedup vs baseline: 1.0299x; 1.0299x over previous
//
#include <hip/hip_runtime.h>
#include <stdint.h>

#define N_NODES 100000
#define N_EDGES 1000000
#define DIM 256
#define CAP 32            // fixed neighbor-slot capacity per node (Poisson(10) graph)

typedef __attribute__((ext_vector_type(8))) short short8;          // bf16 MFMA frag (4 VGPR)
typedef __attribute__((ext_vector_type(4))) float f32x4;           // fp32 C/D frag / NT ops
typedef __attribute__((ext_vector_type(4))) unsigned short u16x4;  // 8B bf16 chunk

__device__ inline float b2f(unsigned short u) {
    union { unsigned int i; float f; } v; v.i = ((unsigned int)u) << 16; return v.f;
}
__device__ inline unsigned short f2b(float f) {   // round-to-nearest-even
    union { float f; unsigned int i; } v; v.f = f;
    unsigned int u = v.i;
    return (unsigned short)((u + 0x7FFFu + ((u >> 16) & 1u)) >> 16);
}

// ---------------- workspace layout (bytes) ----------------
// cnt    u32 N          @ 0          (raw in-degree; may exceed CAP)
// ovfCnt u32            @ 400000
// colM   i32 N*CAP      @ 400256     (12.8 MB; NOT zeroed — gather clamps indices)
// wgt    f32 N          @ 13200256   (rsqrt(cnt+1), precomputed once)
// ovf    u32 pairs E    @ 13600256   (8 MB: worst-case-correct overflow list)
// Wt1    bf16 256x256   @ 21600256   (n-major, k contiguous)
// Wt2    bf16 256x256   @ 21731328
// xs     bf16 N*256     @ 21862400   (raw bf16 features)
// z1s    bf16 N*256     @ 73062400   (raw bf16 layer-1 relu output)
// memset range [0, 400256) covers cnt | ovfCnt only.

#define NB_FILL 245    // ceil(1M / 4096); 16 edges/thread (ILP-16 atomic chains)
#define NB_PACK 512
#define NB_CVT  25000  // N*256/4 float4 elems / 256 threads

// ONE preprocessing kernel: bucket-fill (blocks [0,245), latency/atomic-bound,
// 16 independent edges per thread to hide the atomicAdd round trip) + W1/W2
// pack + x->bf16 convert (BW-bound, overlaps fill).
__global__ void k_pre(const int* __restrict__ src, const int* __restrict__ dst,
                      uint32_t* __restrict__ cnt, uint32_t* __restrict__ ovfCnt,
                      int* __restrict__ colM, uint32_t* __restrict__ ovf,
                      const float* __restrict__ W1, const float* __restrict__ W2,
                      unsigned short* __restrict__ Wt1, unsigned short* __restrict__ Wt2,
                      const float* __restrict__ x, unsigned short* __restrict__ xs) {
    int b = blockIdx.x, t = threadIdx.x;
    if (b < NB_FILL) {
        int e = b * 4096 + t;
        #pragma unroll
        for (int k = 0; k < 16; ++k, e += 256) {   // 16 independent atomic chains
            if (e < N_EDGES) {
                unsigned d = (unsigned)dst[e];
                unsigned s = (unsigned)src[e];
                if (d < N_NODES && s < N_NODES) {
                    uint32_t p = atomicAdd(&cnt[d], 1u);
                    if (p < CAP) colM[(size_t)d * CAP + p] = (int)s;
                    else {       // correctness fallback; statistically never taken
                        uint32_t o = atomicAdd(ovfCnt, 1u);
                        if (o < (uint32_t)N_EDGES) { ovf[2 * o] = d; ovf[2 * o + 1] = s; }
                    }
                }
            }
        }
    } else if (b < NB_FILL + NB_PACK) {
        int n = b - NB_FILL;
        if (n < 256) Wt1[n * 256 + t] = f2b(W1[t * 256 + n]);
        else { n -= 256; Wt2[n * 256 + t] = f2b(W2[t * 256 + n]); }
    } else {
        int i = (b - (NB_FILL + NB_PACK)) * 256 + t;   // float4 index, exactly N*64
        f32x4 v = __builtin_nontemporal_load((const f32x4*)x + i);  // read-once stream
        u16x4 o;
        o.x = f2b(v.x); o.y = f2b(v.y); o.z = f2b(v.z); o.w = f2b(v.w);
        *((u16x4*)xs + i) = o;                          // re-read by gather -> cacheable
    }
}

// wgt[n] = rsqrt(cnt[n]+1): hoists the per-edge int->float + rsqrt out of the
// gather hot loop.
__global__ void k_wgt(const uint32_t* __restrict__ cnt, float* __restrict__ wgt) {
    int n = blockIdx.x * blockDim.x + threadIdx.x;
    if (n < N_NODES) wgt[n] = rsqrtf((float)(cnt[n] + 1u));
}

// Fused gather + GEMM per 64-node block — 512 threads / 8 waves, engineered
// for the 64-TOTAL-reg bucket (8 waves/SIMD, 32 waves/CU).
//
// Evidence trail: occupancy buckets are at <=64 / <=128 total (VGPR+AGPR,
// unified file) regs/wave (rounds 3/5/6). Round-6 fused = 64V+64A = 128 ->
// 16 waves/CU, 2.8 TB/s. Round-7 de-fused gather = 32 VGPR -> 22 waves/CU,
// 3.6 TB/s — SAME BW as fused at an occupancy plateau => ~3.6 TB/s is the
// random-512B-row service ceiling, and de-fusion's agg round-trip + extra
// GEMM pass made it a net loss. This kernel keeps fusion AND the small
// register footprint: gather phase = round-7's exact 32-VGPR full-wave
// u16x4 body (one wave = one node, 8 nodes sequentially); GEMM phase = 8
// waves x 32 output cols -> acc[4][2] = 32 AGPR, ONE xf fragment live at a
// time (xf + wf0/wf1 = 12 VGPR). Target 32V+32A = 64 exactly;
// __launch_bounds__(512,8) forces it. Failure signature if the estimate is
// wrong: WRITE_SIZE balloons (scratch spill) -> revert to round-6 fused.
//
// colM is NOT zeroed: indices clamped with min(ix,N-1); (j+i<dg ? w : 0)
// masks the contribution (0 * finite = 0, no NaN). Per-element fma chain
// order is IDENTICAL to rounds 4-7 (absmax sits at threshold).
//
// LDS: gathered row nl is stored as one b64/lane with 16B-chunk XOR swizzle
// (chunk c -> c ^ (nl&7)) — a pure permutation of the contiguous 512 B row
// (no extra bank conflicts); GEMM reads short8 at the same swizzle, so each
// 16 B fragment stays contiguous.
__global__ __launch_bounds__(512, 8) void k_fused(
        const unsigned short* __restrict__ rows, const uint32_t* __restrict__ cnt,
        const float* __restrict__ wgt,
        const uint32_t* __restrict__ ovfCnt, const int* __restrict__ colM,
        const uint32_t* __restrict__ ovf, const unsigned short* __restrict__ Wt,
        const float* __restrict__ bias,
        unsigned short* __restrict__ Cb, float* __restrict__ Cf) {
    __shared__ __align__(16) unsigned short As[64 * 256];   // 32768 B, swizzled

    int tid = threadIdx.x;
    int w = tid >> 6, lane = tid & 63;
    int rowBase = blockIdx.x * 64;
    uint32_t ovfN = *ovfCnt;
    const u16x4* r4 = (const u16x4*)rows;

    // ---- phase 1: gather; wave w owns nodes rowBase + w*8 .. +7 ----
    #pragma unroll 1
    for (int s = 0; s < 8; ++s) {
        int nl    = w * 8 + s;                 // local row 0..63
        int node  = rowBase + nl;
        bool valid = node < N_NODES;
        int nsafe = valid ? node : 0;

        uint32_t dgRaw = cnt[nsafe];                    // true degree (may exceed CAP)
        float    di    = wgt[nsafe];                    // rsqrt(deg+1), precomputed
        uint32_t dg    = valid ? (dgRaw < CAP ? dgRaw : CAP) : 0u;
        float    wSelf = valid ? di : 0.f;

        u16x4 sv = r4[(size_t)nsafe * 64 + lane];       // self row (raw bf16)
        float a[4];
        a[0] = wSelf * b2f(sv.x); a[1] = wSelf * b2f(sv.y);
        a[2] = wSelf * b2f(sv.z); a[3] = wSelf * b2f(sv.w);

        const int* cp = colM + (size_t)nsafe * CAP;
        for (uint32_t j = 0; j < dg; j += 8) {          // wave-uniform trip count
            int4 i0 = *(const int4*)(cp + j);           // 8 raw indices (bcast)
            int4 i1 = *(const int4*)(cp + j + 4);
            unsigned x0 = min((unsigned)i0.x, N_NODES - 1u);
            unsigned x1 = min((unsigned)i0.y, N_NODES - 1u);
            unsigned x2 = min((unsigned)i0.z, N_NODES - 1u);
            unsigned x3 = min((unsigned)i0.w, N_NODES - 1u);
            unsigned x4 = min((unsigned)i1.x, N_NODES - 1u);
            unsigned x5 = min((unsigned)i1.y, N_NODES - 1u);
            unsigned x6 = min((unsigned)i1.z, N_NODES - 1u);
            unsigned x7 = min((unsigned)i1.w, N_NODES - 1u);
            u16x4 r0 = r4[(size_t)x0 * 64 + lane];      // 8 independent 8B row loads
            u16x4 r1 = r4[(size_t)x1 * 64 + lane];      // (512 B/wave each, in flight)
            u16x4 r2 = r4[(size_t)x2 * 64 + lane];
            u16x4 r3 = r4[(size_t)x3 * 64 + lane];
            u16x4 r4v = r4[(size_t)x4 * 64 + lane];
            u16x4 r5 = r4[(size_t)x5 * 64 + lane];
            u16x4 r6 = r4[(size_t)x6 * 64 + lane];
            u16x4 r7 = r4[(size_t)x7 * 64 + lane];
            float w0 = (j + 0 < dg) ? wgt[x0] : 0.f;    // wave-uniform bcast loads
            float w1 = (j + 1 < dg) ? wgt[x1] : 0.f;
            float w2 = (j + 2 < dg) ? wgt[x2] : 0.f;
            float w3 = (j + 3 < dg) ? wgt[x3] : 0.f;
            float w4 = (j + 4 < dg) ? wgt[x4] : 0.f;
            float w5 = (j + 5 < dg) ? wgt[x5] : 0.f;
            float w6 = (j + 6 < dg) ? wgt[x6] : 0.f;
            float w7 = (j + 7 < dg) ? wgt[x7] : 0.f;
            #pragma unroll
            for (int i = 0; i < 4; ++i) {               // identical chain order
                float sacc = fmaf(w0, b2f(r0[i]), a[i]);
                sacc = fmaf(w1, b2f(r1[i]), sacc);
                sacc = fmaf(w2, b2f(r2[i]), sacc);
                sacc = fmaf(w3, b2f(r3[i]), sacc);
                sacc = fmaf(w4, b2f(r4v[i]), sacc);
                sacc = fmaf(w5, b2f(r5[i]), sacc);
                sacc = fmaf(w6, b2f(r6[i]), sacc);
                sacc = fmaf(w7, b2f(r7[i]), sacc);
                a[i] = sacc;
            }
        }

        if (ovfN) {   // correctness-only path; never taken for this graph
            for (uint32_t k = 0; k < ovfN; ++k) {
                uint32_t od = ovf[2 * k], os = ovf[2 * k + 1];
                if (valid && od == (uint32_t)node) {
                    float wv = wgt[os];
                    u16x4 rv = r4[(size_t)os * 64 + lane];
                    #pragma unroll
                    for (int i = 0; i < 4; ++i) a[i] = fmaf(wv, b2f(rv[i]), a[i]);
                }
            }
        }

        u16x4 o;
        o.x = f2b(di * a[0]); o.y = f2b(di * a[1]);
        o.z = f2b(di * a[2]); o.w = f2b(di * a[3]);
        // b64 store into swizzled tile: chunk (lane>>1) -> ^(nl&7), half (lane&1)
        *(u16x4*)((char*)As + nl * 512 + ((((lane >> 1)) ^ (nl & 7)) << 4) + (lane & 1) * 8) = o;
    }
    __syncthreads();

    // ---- phase 2: GEMM, swapped operands; wave w -> cols [w*32, w*32+32) ----
    int m = lane & 15, quad = lane >> 4;

    f32x4 acc[4][2];
    #pragma unroll
    for (int mt = 0; mt < 4; ++mt) {
        acc[mt][0] = (f32x4){0.f, 0.f, 0.f, 0.f};
        acc[mt][1] = (f32x4){0.f, 0.f, 0.f, 0.f};
    }

    #pragma unroll
    for (int ks = 0; ks < 8; ++ks) {          // K = 8 steps x 32
        short8 wf0 = *(const short8*)(Wt + (size_t)(w * 32 + m)      * 256 + ks * 32 + quad * 8);
        short8 wf1 = *(const short8*)(Wt + (size_t)(w * 32 + 16 + m) * 256 + ks * 32 + quad * 8);
        #pragma unroll
        for (int mt = 0; mt < 4; ++mt) {       // ONE xf live at a time (reg cap)
            int rl = mt * 16 + m;
            int ch = (ks * 4 + quad) ^ (rl & 7);
            short8 xf = *(const short8*)((const char*)As + rl * 512 + (ch << 4));
            acc[mt][0] = __builtin_amdgcn_mfma_f32_16x16x32_bf16(wf0, xf, acc[mt][0], 0, 0, 0);
            acc[mt][1] = __builtin_amdgcn_mfma_f32_16x16x32_bf16(wf1, xf, acc[mt][1], 0, 0, 0);
        }
    }

    // epilogue: D row (quad*4+r) = output col, D col (lane&15) = node
    float4 bv0 = *(const float4*)(bias + w * 32 + quad * 4);
    float4 bv1 = *(const float4*)(bias + w * 32 + 16 + quad * 4);

    #pragma unroll
    for (int mt = 0; mt < 4; ++mt) {
        int node = rowBase + mt * 16 + m;
        if (node >= N_NODES) continue;
        int c0 = w * 32 + quad * 4;
        if (Cf) {
            f32x4 v0 = acc[mt][0], v1 = acc[mt][1];
            f32x4 o0, o1;
            o0.x = fmaxf(v0[0] + bv0.x, 0.f); o0.y = fmaxf(v0[1] + bv0.y, 0.f);
            o0.z = fmaxf(v0[2] + bv0.z, 0.f); o0.w = fmaxf(v0[3] + bv0.w, 0.f);
            o1.x = fmaxf(v1[0] + bv1.x, 0.f); o1.y = fmaxf(v1[1] + bv1.y, 0.f);
            o1.z = fmaxf(v1[2] + bv1.z, 0.f); o1.w = fmaxf(v1[3] + bv1.w, 0.f);
            // final output never re-read -> NT stores, keep caches for gather rows
            __builtin_nontemporal_store(o0, (f32x4*)(Cf + (size_t)node * 256 + c0));
            __builtin_nontemporal_store(o1, (f32x4*)(Cf + (size_t)node * 256 + c0 + 16));
        } else {
            f32x4 v0 = acc[mt][0], v1 = acc[mt][1];
            u16x4 o0, o1;   // raw relu, bf16 (layer-2 gather applies weights itself)
            o0.x = f2b(fmaxf(v0[0] + bv0.x, 0.f)); o0.y = f2b(fmaxf(v0[1] + bv0.y, 0.f));
            o0.z = f2b(fmaxf(v0[2] + bv0.z, 0.f)); o0.w = f2b(fmaxf(v0[3] + bv0.w, 0.f));
            o1.x = f2b(fmaxf(v1[0] + bv1.x, 0.f)); o1.y = f2b(fmaxf(v1[1] + bv1.y, 0.f));
            o1.z = f2b(fmaxf(v1[2] + bv1.z, 0.f)); o1.w = f2b(fmaxf(v1[3] + bv1.w, 0.f));
            *(u16x4*)(Cb + (size_t)node * 256 + c0)      = o0;
            *(u16x4*)(Cb + (size_t)node * 256 + c0 + 16) = o1;
        }
    }
}

extern "C" void kernel_launch(void* const* d_in, const int* in_sizes, int n_in,
                              void* d_out, int out_size, void* d_ws, size_t ws_size,
                              hipStream_t stream) {
    const int*   edge = (const int*)d_in[0];   // [2][E]: row0 = src, row1 = dst
    const float* x    = (const float*)d_in[1];
    const float* W1   = (const float*)d_in[2];
    const float* b1   = (const float*)d_in[3];
    const float* W2   = (const float*)d_in[4];
    const float* b2   = (const float*)d_in[5];
    float* out = (float*)d_out;

    char* ws = (char*)d_ws;
    uint32_t*       cnt    = (uint32_t*)(ws + 0);
    uint32_t*       ovfCnt = (uint32_t*)(ws + 400000);
    int*            colM   = (int*)     (ws + 400256);
    float*          wgt    = (float*)   (ws + 13200256);
    uint32_t*       ovf    = (uint32_t*)(ws + 13600256);
    unsigned short* Wt1    = (unsigned short*)(ws + 21600256);
    unsigned short* Wt2    = (unsigned short*)(ws + 21731328);
    unsigned short* xs     = (unsigned short*)(ws + 21862400);
    unsigned short* z1s    = (unsigned short*)(ws + 73062400ull);

    const int* src = edge;
    const int* dst = edge + N_EDGES;

    // zero cnt + ovfCnt only (colM not zeroed: gather clamps indices)
    hipMemsetAsync(ws, 0, 400256, stream);

    // all heavy preprocessing in one launch: fill || pack || cvt
    k_pre<<<NB_FILL + NB_PACK + NB_CVT, 256, 0, stream>>>(
        src, dst, cnt, ovfCnt, colM, ovf, W1, W2, Wt1, Wt2, x, xs);
    // tiny: per-node weight table
    k_wgt<<<(N_NODES + 255) / 256, 256, 0, stream>>>(cnt, wgt);

    // layer 1: fused gather+GEMM (8 waves, 64-reg bucket), writes bf16 z1s
    k_fused<<<(N_NODES + 63) / 64, 512, 0, stream>>>(
        xs, cnt, wgt, ovfCnt, colM, ovf, Wt1, b1, z1s, nullptr);
    // layer 2: fused gather+GEMM, writes fp32 output
    k_fused<<<(N_NODES + 63) / 64, 512, 0, stream>>>(
        z1s, cnt, wgt, ovfCnt, colM, ovf, Wt2, b2, nullptr, out);
}

// Round 9
// 431.035 us; speedup vs baseline: 1.0863x; 1.0547x over previous
//
#include <hip/hip_runtime.h>
#include <stdint.h>

#define N_NODES 100000
#define N_EDGES 1000000
#define DIM 256
#define CAP 32            // fixed neighbor-slot capacity per node (Poisson(10) graph)

typedef __attribute__((ext_vector_type(8))) short short8;          // bf16 MFMA frag (4 VGPR)
typedef __attribute__((ext_vector_type(8))) unsigned short u16x8;  // 16B row chunk
typedef __attribute__((ext_vector_type(4))) float f32x4;           // fp32 C/D frag / NT ops
typedef __attribute__((ext_vector_type(4))) unsigned short u16x4;  // 8B bf16 store

__device__ inline float b2f(unsigned short u) {
    union { unsigned int i; float f; } v; v.i = ((unsigned int)u) << 16; return v.f;
}
__device__ inline unsigned short f2b(float f) {   // round-to-nearest-even
    union { float f; unsigned int i; } v; v.f = f;
    unsigned int u = v.i;
    return (unsigned short)((u + 0x7FFFu + ((u >> 16) & 1u)) >> 16);
}

// ---------------- workspace layout (bytes) ----------------
// cntP   u32 N*16       @ 0          (PADDED: one counter per 64-B line ->
//                                     fill atomics suffer ~10 same-line RMWs
//                                     instead of ~160; 6.4 MB, memset'd)
// ovfCnt u32            @ 6400000
// colM   i32 N*CAP      @ 6400256    (12.8 MB; NOT zeroed — gather clamps)
// cnt    u32 N          @ 19200256   (compact, written by k_wgt)
// wgt    f32 N          @ 19600256   (rsqrt(cnt+1), written by k_wgt)
// ovf    u32 pairs E    @ 20000256   (8 MB: worst-case-correct overflow list)
// Wt1    bf16 256x256   @ 28000256   (n-major, k contiguous)
// Wt2    bf16 256x256   @ 28131328
// xs     bf16 N*256     @ 28262400   (raw bf16 features)
// z1s    bf16 N*256     @ 79462400   (raw bf16 layer-1 relu output)
// memset range [0, 6400260) covers cntP | ovfCnt.

#define NB_FILL 245    // ceil(1M / 4096); 16 edges/thread (ILP-16 atomic chains)
#define NB_PACK 512
#define NB_CVT  25000  // N*256/4 float4 elems / 256 threads

// ONE preprocessing kernel: bucket-fill (blocks [0,245), latency/atomic-bound,
// 16 independent edges/thread; atomics hit line-padded cntP) + W1/W2 pack +
// x->bf16 convert (BW-bound, overlaps fill).
__global__ void k_pre(const int* __restrict__ src, const int* __restrict__ dst,
                      uint32_t* __restrict__ cntP, uint32_t* __restrict__ ovfCnt,
                      int* __restrict__ colM, uint32_t* __restrict__ ovf,
                      const float* __restrict__ W1, const float* __restrict__ W2,
                      unsigned short* __restrict__ Wt1, unsigned short* __restrict__ Wt2,
                      const float* __restrict__ x, unsigned short* __restrict__ xs) {
    int b = blockIdx.x, t = threadIdx.x;
    if (b < NB_FILL) {
        int e = b * 4096 + t;
        #pragma unroll
        for (int k = 0; k < 16; ++k, e += 256) {   // 16 independent atomic chains
            if (e < N_EDGES) {
                unsigned d = (unsigned)dst[e];
                unsigned s = (unsigned)src[e];
                if (d < N_NODES && s < N_NODES) {
                    uint32_t p = atomicAdd(&cntP[(size_t)d * 16], 1u);  // padded line
                    if (p < CAP) colM[(size_t)d * CAP + p] = (int)s;
                    else {       // correctness fallback; statistically never taken
                        uint32_t o = atomicAdd(ovfCnt, 1u);
                        if (o < (uint32_t)N_EDGES) { ovf[2 * o] = d; ovf[2 * o + 1] = s; }
                    }
                }
            }
        }
    } else if (b < NB_FILL + NB_PACK) {
        int n = b - NB_FILL;
        if (n < 256) Wt1[n * 256 + t] = f2b(W1[t * 256 + n]);
        else { n -= 256; Wt2[n * 256 + t] = f2b(W2[t * 256 + n]); }
    } else {
        int i = (b - (NB_FILL + NB_PACK)) * 256 + t;   // float4 index, exactly N*64
        f32x4 v = __builtin_nontemporal_load((const f32x4*)x + i);  // read-once stream
        u16x4 o;
        o.x = f2b(v.x); o.y = f2b(v.y); o.z = f2b(v.z); o.w = f2b(v.w);
        *((u16x4*)xs + i) = o;                          // re-read by gather -> cacheable
    }
}

// Compact cntP -> cnt and precompute wgt = rsqrt(cnt+1). Keeps the gather
// kernel's loads byte-identical to round 6 (compact cnt + wgt tables).
__global__ void k_wgt(const uint32_t* __restrict__ cntP, uint32_t* __restrict__ cnt,
                      float* __restrict__ wgt) {
    int n = blockIdx.x * blockDim.x + threadIdx.x;
    if (n < N_NODES) {
        uint32_t c = cntP[(size_t)n * 16];
        cnt[n] = c;
        wgt[n] = rsqrtf((float)(c + 1u));
    }
}

// Fused gather + GEMM per 64-node block (4 waves) — ROUND-6 CONFIGURATION,
// VERBATIM. Evidence (rounds 3/5/6/8): occupancy buckets at <=64/<=128 total
// regs; this kernel = 64 VGPR + 64 AGPR = 128 exactly -> 16 waves/CU. Round-8
// proved restructuring for the 64-bucket (sequential nodes per wave) LOSES
// (2.5 vs 2.8 TB/s): in-order waves expose per-node latency. The half-wave
// PAIR body below (2 nodes per iteration, 8x 16B loads in flight) is the best
// fused gather measured. DO NOT perturb.
__global__ __launch_bounds__(256, 4) void k_fused(
        const unsigned short* __restrict__ rows, const uint32_t* __restrict__ cnt,
        const float* __restrict__ wgt,
        const uint32_t* __restrict__ ovfCnt, const int* __restrict__ colM,
        const uint32_t* __restrict__ ovf, const unsigned short* __restrict__ Wt,
        const float* __restrict__ bias,
        unsigned short* __restrict__ Cb, float* __restrict__ Cf) {
    __shared__ __align__(16) unsigned short As[64 * 256];   // 32768 B, swizzled

    int tid = threadIdx.x;
    int w = tid >> 6, lane = tid & 63;
    int hl = lane & 31, half = lane >> 5;
    int rowBase = blockIdx.x * 64;
    uint32_t ovfN = *ovfCnt;

    // ---- phase 1: gather 16 nodes/wave as 8 half-wave pairs ----
    const u16x8* r8 = (const u16x8*)rows;
    #pragma unroll 1
    for (int t = 0; t < 8; ++t) {
        int nl    = w * 16 + t * 2 + half;     // local row 0..63
        int node  = rowBase + nl;
        bool valid = node < N_NODES;
        int nsafe = valid ? node : 0;

        uint32_t dgRaw = cnt[nsafe];                    // true degree (may exceed CAP)
        float    di    = wgt[nsafe];                    // rsqrt(deg+1), precomputed
        uint32_t dg    = valid ? (dgRaw < CAP ? dgRaw : CAP) : 0u;
        float    wSelf = valid ? di : 0.f;

        u16x8 sv = r8[(size_t)nsafe * 32 + hl];         // self row (raw bf16)
        float a[8];
        #pragma unroll
        for (int i = 0; i < 8; ++i) a[i] = wSelf * b2f(sv[i]);

        uint32_t dgo   = (uint32_t)__shfl((int)dg, lane ^ 32);
        uint32_t dgMax = dg > dgo ? dg : dgo;
        const int* cp  = colM + (size_t)nsafe * CAP;

        for (uint32_t j = 0; j < dgMax; j += 8) {       // <=4 iters; no branches inside
            int4 i0 = *(const int4*)(cp + j);           // 8 raw indices (tail = garbage)
            int4 i1 = *(const int4*)(cp + j + 4);
            // clamp: garbage/tail slots -> valid node, masked by w=0 below
            unsigned x0 = min((unsigned)i0.x, N_NODES - 1u);
            unsigned x1 = min((unsigned)i0.y, N_NODES - 1u);
            unsigned x2 = min((unsigned)i0.z, N_NODES - 1u);
            unsigned x3 = min((unsigned)i0.w, N_NODES - 1u);
            unsigned x4 = min((unsigned)i1.x, N_NODES - 1u);
            unsigned x5 = min((unsigned)i1.y, N_NODES - 1u);
            unsigned x6 = min((unsigned)i1.z, N_NODES - 1u);
            unsigned x7 = min((unsigned)i1.w, N_NODES - 1u);
            u16x8 r0 = r8[(size_t)x0 * 32 + hl];        // 8 independent 16B row loads
            u16x8 r1 = r8[(size_t)x1 * 32 + hl];
            u16x8 r2 = r8[(size_t)x2 * 32 + hl];
            u16x8 r3 = r8[(size_t)x3 * 32 + hl];
            u16x8 r4 = r8[(size_t)x4 * 32 + hl];
            u16x8 r5 = r8[(size_t)x5 * 32 + hl];
            u16x8 r6 = r8[(size_t)x6 * 32 + hl];
            u16x8 r7 = r8[(size_t)x7 * 32 + hl];
            float w0 = (j + 0 < dg) ? wgt[x0] : 0.f;    // broadcast f32 loads
            float w1 = (j + 1 < dg) ? wgt[x1] : 0.f;
            float w2 = (j + 2 < dg) ? wgt[x2] : 0.f;
            float w3 = (j + 3 < dg) ? wgt[x3] : 0.f;
            float w4 = (j + 4 < dg) ? wgt[x4] : 0.f;
            float w5 = (j + 5 < dg) ? wgt[x5] : 0.f;
            float w6 = (j + 6 < dg) ? wgt[x6] : 0.f;
            float w7 = (j + 7 < dg) ? wgt[x7] : 0.f;
            #pragma unroll
            for (int i = 0; i < 8; ++i) {
                float s = fmaf(w0, b2f(r0[i]), a[i]);
                s = fmaf(w1, b2f(r1[i]), s);
                s = fmaf(w2, b2f(r2[i]), s);
                s = fmaf(w3, b2f(r3[i]), s);
                s = fmaf(w4, b2f(r4[i]), s);
                s = fmaf(w5, b2f(r5[i]), s);
                s = fmaf(w6, b2f(r6[i]), s);
                s = fmaf(w7, b2f(r7[i]), s);
                a[i] = s;
            }
        }

        if (ovfN) {   // correctness-only path; never taken for this graph
            for (uint32_t k = 0; k < ovfN; ++k) {
                uint32_t od = ovf[2 * k], os = ovf[2 * k + 1];
                if (valid && od == (uint32_t)node) {
                    float wv = wgt[os];
                    u16x8 rv = r8[(size_t)os * 32 + hl];
                    #pragma unroll
                    for (int i = 0; i < 8; ++i) a[i] = fmaf(wv, b2f(rv[i]), a[i]);
                }
            }
        }

        short8 o;
        #pragma unroll
        for (int i = 0; i < 8; ++i) o[i] = (short)f2b(di * a[i]);
        // swizzled write: logical chunk hl -> physical chunk hl ^ (row&7)
        *(short8*)((char*)As + nl * 512 + ((hl ^ (nl & 7)) << 4)) = o;
    }
    __syncthreads();

    // ---- phase 2: GEMM, swapped operands ----
    int m = lane & 15, quad = lane >> 4;

    f32x4 acc[4][4];
    #pragma unroll
    for (int mt = 0; mt < 4; ++mt)
        #pragma unroll
        for (int nt = 0; nt < 4; ++nt)
            acc[mt][nt] = (f32x4){0.f, 0.f, 0.f, 0.f};

    #pragma unroll
    for (int ks = 0; ks < 8; ++ks) {          // K = 8 steps x 32
        short8 wf[4], xf[4];
        #pragma unroll
        for (int nt = 0; nt < 4; ++nt)
            wf[nt] = *(const short8*)(Wt + (size_t)(w * 64 + nt * 16 + m) * 256 + ks * 32 + quad * 8);
        #pragma unroll
        for (int mt = 0; mt < 4; ++mt) {
            int rl = mt * 16 + m;
            int ch = (ks * 4 + quad) ^ (rl & 7);
            xf[mt] = *(const short8*)((const char*)As + rl * 512 + (ch << 4));
        }
        #pragma unroll
        for (int mt = 0; mt < 4; ++mt)
            #pragma unroll
            for (int nt = 0; nt < 4; ++nt)
                acc[mt][nt] = __builtin_amdgcn_mfma_f32_16x16x32_bf16(
                    wf[nt], xf[mt], acc[mt][nt], 0, 0, 0);
    }

    // epilogue: D row (quad*4+r) = output col, D col (lane&15) = node
    float4 bv[4];
    #pragma unroll
    for (int nt = 0; nt < 4; ++nt)
        bv[nt] = *(const float4*)(bias + w * 64 + nt * 16 + quad * 4);

    #pragma unroll
    for (int mt = 0; mt < 4; ++mt) {
        int node = rowBase + mt * 16 + m;
        if (node >= N_NODES) continue;
        if (Cf) {
            #pragma unroll
            for (int nt = 0; nt < 4; ++nt) {
                int c = w * 64 + nt * 16 + quad * 4;
                f32x4 v = acc[mt][nt];
                f32x4 o;
                o.x = fmaxf(v[0] + bv[nt].x, 0.f);
                o.y = fmaxf(v[1] + bv[nt].y, 0.f);
                o.z = fmaxf(v[2] + bv[nt].z, 0.f);
                o.w = fmaxf(v[3] + bv[nt].w, 0.f);
                // final output never re-read -> NT store, keep caches for gather rows
                __builtin_nontemporal_store(o, (f32x4*)(Cf + (size_t)node * 256 + c));
            }
        } else {
            #pragma unroll
            for (int nt = 0; nt < 4; ++nt) {
                int c = w * 64 + nt * 16 + quad * 4;
                f32x4 v = acc[mt][nt];
                u16x4 o;   // raw relu, bf16 (layer-2 gather applies weights itself)
                o.x = f2b(fmaxf(v[0] + bv[nt].x, 0.f));
                o.y = f2b(fmaxf(v[1] + bv[nt].y, 0.f));
                o.z = f2b(fmaxf(v[2] + bv[nt].z, 0.f));
                o.w = f2b(fmaxf(v[3] + bv[nt].w, 0.f));
                *(u16x4*)(Cb + (size_t)node * 256 + c) = o;
            }
        }
    }
}

extern "C" void kernel_launch(void* const* d_in, const int* in_sizes, int n_in,
                              void* d_out, int out_size, void* d_ws, size_t ws_size,
                              hipStream_t stream) {
    const int*   edge = (const int*)d_in[0];   // [2][E]: row0 = src, row1 = dst
    const float* x    = (const float*)d_in[1];
    const float* W1   = (const float*)d_in[2];
    const float* b1   = (const float*)d_in[3];
    const float* W2   = (const float*)d_in[4];
    const float* b2   = (const float*)d_in[5];
    float* out = (float*)d_out;

    char* ws = (char*)d_ws;
    uint32_t*       cntP   = (uint32_t*)(ws + 0);
    uint32_t*       ovfCnt = (uint32_t*)(ws + 6400000);
    int*            colM   = (int*)     (ws + 6400256);
    uint32_t*       cnt    = (uint32_t*)(ws + 19200256);
    float*          wgt    = (float*)   (ws + 19600256);
    uint32_t*       ovf    = (uint32_t*)(ws + 20000256);
    unsigned short* Wt1    = (unsigned short*)(ws + 28000256);
    unsigned short* Wt2    = (unsigned short*)(ws + 28131328);
    unsigned short* xs     = (unsigned short*)(ws + 28262400);
    unsigned short* z1s    = (unsigned short*)(ws + 79462400ull);

    const int* src = edge;
    const int* dst = edge + N_EDGES;

    // zero cntP + ovfCnt (colM not zeroed: gather clamps indices)
    hipMemsetAsync(ws, 0, 6400260, stream);

    // all heavy preprocessing in one launch: fill || pack || cvt
    k_pre<<<NB_FILL + NB_PACK + NB_CVT, 256, 0, stream>>>(
        src, dst, cntP, ovfCnt, colM, ovf, W1, W2, Wt1, Wt2, x, xs);
    // tiny: compact counters + per-node weight table
    k_wgt<<<(N_NODES + 255) / 256, 256, 0, stream>>>(cntP, cnt, wgt);

    // layer 1: fused gather+GEMM (round-6 config), writes raw relu bf16 z1s
    k_fused<<<(N_NODES + 63) / 64, 256, 0, stream>>>(
        xs, cnt, wgt, ovfCnt, colM, ovf, Wt1, b1, z1s, nullptr);
    // layer 2: fused gather+GEMM, writes fp32 output
    k_fused<<<(N_NODES + 63) / 64, 256, 0, stream>>>(
        z1s, cnt, wgt, ovfCnt, colM, ovf, Wt2, b2, nullptr, out);
}